// Round 7
// baseline (229.462 us; speedup 1.0000x reference)
//
#include <hip/hip_runtime.h>

#define TOKENS 16384
#define EMB 4096
#define NEXP 64

typedef __attribute__((ext_vector_type(8))) short short8;
typedef __attribute__((ext_vector_type(4))) float f32x4;
typedef __attribute__((ext_vector_type(4))) unsigned short ush4;

#define WP_USHORTS (3 * NEXP * EMB)        // 786432 ushorts = 1.5 MB
#define WP_FLOATS  (WP_USHORTS / 2)        // 393216 floats

// fp32 -> 3x bf16: hi round-nearest (err 2^-9), mid/lo trunc (2^-17/2^-25);
// residual 2^-27 rel. Dropped cross terms ml/lm/ll ~2^-27 -> ~1e-8 rms/logit.
__device__ __forceinline__ void split3(float x, unsigned short& h,
                                       unsigned short& m, unsigned short& l) {
    unsigned u = __float_as_uint(x);
    unsigned r = u + 0x7FFFu + ((u >> 16) & 1u);       // RN to bf16
    float hF = __uint_as_float(r & 0xFFFF0000u);
    h = (unsigned short)(r >> 16);
    float r1 = x - hF;                                 // exact (Sterbenz-ish)
    unsigned u1 = __float_as_uint(r1);
    float mF = __uint_as_float(u1 & 0xFFFF0000u);      // trunc
    m = (unsigned short)(u1 >> 16);
    float r2 = r1 - mF;                                // exact
    l = (unsigned short)(__float_as_uint(r2) >> 16);   // trunc
}

// prep: split W (64x4096 fp32, 1 MB) into 3 bf16 planes Wp[plane][e][k]
__global__ __launch_bounds__(256) void split_w(const float* __restrict__ W,
                                               unsigned short* __restrict__ Wp) {
    const int i = (blockIdx.x * 256 + threadIdx.x) * 4;
    const float4 v = *reinterpret_cast<const float4*>(W + i);
    ush4 h, m, l;
#pragma unroll
    for (int e = 0; e < 4; ++e) {
        unsigned short he, me, le;
        split3(reinterpret_cast<const float*>(&v)[e], he, me, le);
        h[e] = he; m[e] = me; l[e] = le;
    }
    *reinterpret_cast<ush4*>(Wp + i) = h;
    *reinterpret_cast<ush4*>(Wp + NEXP * EMB + i) = m;
    *reinterpret_cast<ush4*>(Wp + 2 * NEXP * EMB + i) = l;
}

// Main: MFMA split-3 bf16 GEMM, NO LDS in the K-loop.
// Wave = 16 tokens x 64 experts (4x 16x16x32 tiles); block = 4 waves;
// grid (256, S) -> 1024 blocks at S=4 = 4 waves/SIMD.
// A-frag: lane l holds x[tok0+(l&15)][kb+(l>>4)*8+e] -> 2 float4 direct
// global loads (each 16-row x 128B-contiguous segments, full lines), split
// in-register to 3 bf16 frags. B-frags: direct 16B loads from L2-resident
// Wp planes. Any HW lane->k permutation cancels (A,B share the slot map);
// C/D layout per guide m89/m91: token=(l>>4)*4+j, expert=(l&15).
// Precision: hh term in its OWN accumulator (small terms ~2^-9 go to a
// second acc) -> total ~1.2e-7 rms = the R3-validated flip-free level.
template<int S>
__global__ __launch_bounds__(256, 4) void router_mfma(
    const float* __restrict__ x, const unsigned short* __restrict__ Wp,
    float* __restrict__ part)
{
    constexpr int KPER = EMB / S;
    constexpr int NST  = KPER / 32;

    __shared__ float sled[4][NEXP * 16];   // 16 KB, epilogue transpose only

    const int t  = threadIdx.x;
    const int w  = t >> 6;
    const int l  = t & 63;
    const int lr = l & 15;     // A token-row / B expert-col
    const int lo = l >> 4;     // k-octet selector
    const int tok0 = (blockIdx.x * 4 + w) * 16;
    const int kb   = blockIdx.y * KPER;

    const float* ax = x + (size_t)(tok0 + lr) * EMB + kb + lo * 8;
    const unsigned short* bw = Wp + (size_t)lr * EMB + kb + lo * 8;

    f32x4 accH[4], accL[4];
#pragma unroll
    for (int et = 0; et < 4; ++et) {
        accH[et] = (f32x4){0.f, 0.f, 0.f, 0.f};
        accL[et] = (f32x4){0.f, 0.f, 0.f, 0.f};
    }

#pragma unroll 1
    for (int ks = 0; ks < NST; ++ks) {
        const float* ap = ax + ks * 32;
        const float4 a0 = *reinterpret_cast<const float4*>(ap);
        const float4 a1 = *reinterpret_cast<const float4*>(ap + 4);
        short8 aH, aM, aL;
#pragma unroll
        for (int e = 0; e < 4; ++e) {
            unsigned short he, me, le;
            split3(reinterpret_cast<const float*>(&a0)[e], he, me, le);
            aH[e] = (short)he; aM[e] = (short)me; aL[e] = (short)le;
            split3(reinterpret_cast<const float*>(&a1)[e], he, me, le);
            aH[4 + e] = (short)he; aM[4 + e] = (short)me; aL[4 + e] = (short)le;
        }
#pragma unroll
        for (int et = 0; et < 4; ++et) {
            const unsigned short* bp = bw + (size_t)et * 16 * EMB + ks * 32;
            const short8 bH = *reinterpret_cast<const short8*>(bp);
            const short8 bM = *reinterpret_cast<const short8*>(bp + NEXP * EMB);
            const short8 bL = *reinterpret_cast<const short8*>(bp + 2 * NEXP * EMB);
            accH[et] = __builtin_amdgcn_mfma_f32_16x16x32_bf16(aH, bH, accH[et], 0, 0, 0);
            accL[et] = __builtin_amdgcn_mfma_f32_16x16x32_bf16(aH, bM, accL[et], 0, 0, 0);
            accL[et] = __builtin_amdgcn_mfma_f32_16x16x32_bf16(aM, bH, accL[et], 0, 0, 0);
            accL[et] = __builtin_amdgcn_mfma_f32_16x16x32_bf16(aM, bM, accL[et], 0, 0, 0);
            accL[et] = __builtin_amdgcn_mfma_f32_16x16x32_bf16(aH, bL, accL[et], 0, 0, 0);
            accL[et] = __builtin_amdgcn_mfma_f32_16x16x32_bf16(aL, bH, accL[et], 0, 0, 0);
        }
    }

    // epilogue: transpose via LDS, then coalesced partial writes
#pragma unroll
    for (int et = 0; et < 4; ++et)
#pragma unroll
        for (int j = 0; j < 4; ++j)
            sled[w][(et * 16 + lr) * 16 + lo * 4 + j] = accH[et][j] + accL[et][j];
    __syncthreads();
#pragma unroll
    for (int r = 0; r < 16; ++r) {
        const int e = r * 4 + lo;
        part[(size_t)(blockIdx.y * NEXP + e) * TOKENS + tok0 + lr]
            = sled[w][e * 16 + lr];
    }
}

// combine splits in fp64 + bias, top-2, softmax (R6-proven).
template<int S>
__global__ __launch_bounds__(256) void reduce_topk(
    const float* __restrict__ part, const float* __restrict__ b,
    float* __restrict__ out)
{
    __shared__ double sv[64][4][2];
    __shared__ int    si[64][4][2];
    const int t    = threadIdx.x;
    const int p4   = t & 3;
    const int slot = t >> 2;
    const int tok  = blockIdx.x * 64 + slot;

    double v[16];
#pragma unroll
    for (int j = 0; j < 16; ++j) v[j] = 0.0;
    for (int s = 0; s < S; ++s)
#pragma unroll
        for (int j = 0; j < 16; ++j)
            v[j] += (double)part[(size_t)((s << 6) + (p4 << 4) + j) * TOKENS + tok];
#pragma unroll
    for (int j = 0; j < 16; ++j) v[j] += (double)b[(p4 << 4) + j];

    double v1 = -1e300, v2 = -1e300; int i1 = 0, i2 = 0;
#pragma unroll
    for (int j = 0; j < 16; ++j) {
        const int e = (p4 << 4) + j;
        if (v[j] > v1)      { v2 = v1; i2 = i1; v1 = v[j]; i1 = e; }
        else if (v[j] > v2) { v2 = v[j]; i2 = e; }
    }
    sv[slot][p4][0] = v1; sv[slot][p4][1] = v2;
    si[slot][p4][0] = i1; si[slot][p4][1] = i2;
    __syncthreads();

    if (p4 == 0) {
        double m1 = -1e300, m2 = -1e300; int j1 = 0, j2 = 0;
#pragma unroll
        for (int p = 0; p < 4; ++p)   // ascending parts: ties keep lowest idx
#pragma unroll
            for (int r = 0; r < 2; ++r) {
                const double vv = sv[slot][p][r]; const int ii = si[slot][p][r];
                if (vv > m1)      { m2 = m1; j2 = j1; m1 = vv; j1 = ii; }
                else if (vv > m2) { m2 = vv; j2 = ii; }
            }
        const float e2  = expf((float)(m2 - m1));   // <= 1
        const float inv = 1.0f / (1.0f + e2);
        out[2 * tok]     = (float)j1;
        out[2 * tok + 1] = (float)j2;
        out[2 * TOKENS + 2 * tok]     = inv;
        out[2 * TOKENS + 2 * tok + 1] = e2 * inv;
    }
}

extern "C" void kernel_launch(void* const* d_in, const int* in_sizes, int n_in,
                              void* d_out, int out_size, void* d_ws, size_t ws_size,
                              hipStream_t stream) {
    const float* x = (const float*)d_in[0];
    const float* W = (const float*)d_in[1];
    const float* b = (const float*)d_in[2];
    float* out = (float*)d_out;
    unsigned short* Wp = (unsigned short*)d_ws;
    float* part = (float*)d_ws + WP_FLOATS;

    split_w<<<dim3(NEXP * EMB / 1024), dim3(256), 0, stream>>>(W, Wp);

    const size_t base = (size_t)WP_FLOATS * 4;
    const size_t per  = (size_t)NEXP * TOKENS * 4;   // 4.19 MB / split
    if (ws_size >= base + 4 * per) {         // 18.3 MB -> 1024 blocks, 4/CU
        router_mfma<4><<<dim3(TOKENS / 64, 4), dim3(256), 0, stream>>>(x, Wp, part);
        reduce_topk<4><<<dim3(TOKENS / 64), dim3(256), 0, stream>>>(part, b, out);
    } else if (ws_size >= base + 2 * per) {  // 9.9 MB
        router_mfma<2><<<dim3(TOKENS / 64, 2), dim3(256), 0, stream>>>(x, Wp, part);
        reduce_topk<2><<<dim3(TOKENS / 64), dim3(256), 0, stream>>>(part, b, out);
    } else {                                 // 5.7 MB
        router_mfma<1><<<dim3(TOKENS / 64, 1), dim3(256), 0, stream>>>(x, Wp, part);
        reduce_topk<1><<<dim3(TOKENS / 64), dim3(256), 0, stream>>>(part, b, out);
    }
}

// Round 8
// 106.327 us; speedup vs baseline: 2.1581x; 2.1581x over previous
//
#include <hip/hip_runtime.h>

#define TOKENS 16384
#define EMB 4096
#define NEXP 64

typedef __attribute__((ext_vector_type(8))) short short8;
typedef __attribute__((ext_vector_type(4))) float f32x4;
typedef __attribute__((ext_vector_type(4))) unsigned short ush4;

#define WP_USHORTS (3 * NEXP * EMB)        // 1.5 MB of bf16 W-planes
#define WP_FLOATS  (WP_USHORTS / 2)

// async global->LDS, 16B/lane; LDS dest = wave-uniform base + lane*16
__device__ __forceinline__ void gl_lds16(const void* g, void* lds) {
    __builtin_amdgcn_global_load_lds(
        (const __attribute__((address_space(1))) void*)g,
        (__attribute__((address_space(3))) void*)lds, 16, 0, 0);
}

// fp32 -> 3x bf16 (R7-verified exact: absmax 0.0): hi RN, mid/lo trunc.
__device__ __forceinline__ void split3(float x, unsigned short& h,
                                       unsigned short& m, unsigned short& l) {
    unsigned u = __float_as_uint(x);
    unsigned r = u + 0x7FFFu + ((u >> 16) & 1u);
    float hF = __uint_as_float(r & 0xFFFF0000u);
    h = (unsigned short)(r >> 16);
    float r1 = x - hF;
    unsigned u1 = __float_as_uint(r1);
    float mF = __uint_as_float(u1 & 0xFFFF0000u);
    m = (unsigned short)(u1 >> 16);
    float r2 = r1 - mF;
    l = (unsigned short)(__float_as_uint(r2) >> 16);
}

// prep: split W into 3 bf16 planes Wp[plane][e][k]
__global__ __launch_bounds__(256) void split_w(const float* __restrict__ W,
                                               unsigned short* __restrict__ Wp) {
    const int i = (blockIdx.x * 256 + threadIdx.x) * 4;
    const float4 v = *reinterpret_cast<const float4*>(W + i);
    ush4 h, m, l;
#pragma unroll
    for (int e = 0; e < 4; ++e) {
        unsigned short he, me, le;
        split3(reinterpret_cast<const float*>(&v)[e], he, me, le);
        h[e] = he; m[e] = me; l[e] = le;
    }
    *reinterpret_cast<ush4*>(Wp + i) = h;
    *reinterpret_cast<ush4*>(Wp + NEXP * EMB + i) = m;
    *reinterpret_cast<ush4*>(Wp + 2 * NEXP * EMB + i) = l;
}

// Main: MFMA split-3 bf16, B staged through LDS (R7 was latency/VMEM bound:
// 9% duty, B re-read 1.6 GB from L2). Per block: 12 KB B-chunk (3 planes x
// 64e x 32k u16) double-buffered via global_load_lds; per-wave B reads are
// 12 ds_read_b128/step with even bank spread (quad=(4*lr+lo)&7: 8 addrs on
// each of 8 quads = b128 floor). A: direct global float4 pair, depth-2 reg
// pipeline; next-iter loads + next-chunk stage issued right AFTER the
// barrier so the following barrier's vmcnt drain lands post-compute.
// Frag/precision scheme identical to R7 (HW-verified exact).
template<int S>
__global__ __launch_bounds__(256, 4) void router_mfma(
    const float* __restrict__ x, const unsigned short* __restrict__ Wp,
    float* __restrict__ part)
{
    constexpr int KPER = EMB / S;
    constexpr int NST  = KPER / 32;

    __shared__ unsigned short sB[2][192][32];   // 24 KB

    const int t  = threadIdx.x;
    const int w  = t >> 6;
    const int l  = t & 63;
    const int lr = l & 15;     // A token-row / B expert-col
    const int lo = l >> 4;     // k-octet selector
    const int tok0 = (blockIdx.x * 4 + w) * 16;
    const int kb   = blockIdx.y * KPER;

    const float* ax = x + (size_t)(tok0 + lr) * EMB + kb + lo * 8;

    // B staging: wave w, instr p (q=3w+p): LDS rows 16q..16q+15, row=plane*64+e;
    // lane l -> row 16q+(l>>2), k-piece (l&3)*8 shorts. Source row in Wp is
    // the same row index (plane-major layout matches), so per-lane source =
    // row*EMB + kb + piece.
    const unsigned short* gb[3];
#pragma unroll
    for (int p = 0; p < 3; ++p) {
        const int q = 3 * w + p;
        gb[p] = Wp + (size_t)(16 * q + (l >> 2)) * EMB + kb + (l & 3) * 8;
    }

    f32x4 accH[4], accL[4];
#pragma unroll
    for (int et = 0; et < 4; ++et) {
        accH[et] = (f32x4){0.f, 0.f, 0.f, 0.f};
        accL[et] = (f32x4){0.f, 0.f, 0.f, 0.f};
    }

    // prologue: stage chunk 0 into buf 0; load A regs for iter 0
#pragma unroll
    for (int p = 0; p < 3; ++p)
        gl_lds16(gb[p], &sB[0][16 * (3 * w + p)][0]);
    float4 a0c = *reinterpret_cast<const float4*>(ax);
    float4 a1c = *reinterpret_cast<const float4*>(ax + 4);

#pragma unroll 1
    for (int ks = 0; ks < NST; ++ks) {
        const int buf = ks & 1;
        __syncthreads();   // chunk ks staged; own vmcnt drained (A regs too)

        // issue next chunk's stage + next A loads NOW (in flight over compute)
        if (ks + 1 < NST) {
#pragma unroll
            for (int p = 0; p < 3; ++p)
                gl_lds16(gb[p] + (ks + 1) * 32, &sB[buf ^ 1][16 * (3 * w + p)][0]);
        }
        const int nk = (ks + 1 < NST ? ks + 1 : ks) * 32;   // clamped: no undef
        float4 a0n = *reinterpret_cast<const float4*>(ax + nk);
        float4 a1n = *reinterpret_cast<const float4*>(ax + nk + 4);

        // split current A into 3 bf16 frags
        short8 aH, aM, aL;
#pragma unroll
        for (int e = 0; e < 4; ++e) {
            unsigned short he, me, le;
            split3(reinterpret_cast<const float*>(&a0c)[e], he, me, le);
            aH[e] = (short)he; aM[e] = (short)me; aL[e] = (short)le;
            split3(reinterpret_cast<const float*>(&a1c)[e], he, me, le);
            aH[4 + e] = (short)he; aM[4 + e] = (short)me; aL[4 + e] = (short)le;
        }

        // B frags from LDS + 6 MFMA per expert-tile
#pragma unroll
        for (int et = 0; et < 4; ++et) {
            const unsigned short* bp = &sB[buf][et * 16 + lr][lo * 8];
            const short8 bH = *reinterpret_cast<const short8*>(bp);
            const short8 bM = *reinterpret_cast<const short8*>(bp + 64 * 32);
            const short8 bL = *reinterpret_cast<const short8*>(bp + 128 * 32);
            accH[et] = __builtin_amdgcn_mfma_f32_16x16x32_bf16(aH, bH, accH[et], 0, 0, 0);
            accL[et] = __builtin_amdgcn_mfma_f32_16x16x32_bf16(aH, bM, accL[et], 0, 0, 0);
            accL[et] = __builtin_amdgcn_mfma_f32_16x16x32_bf16(aM, bH, accL[et], 0, 0, 0);
            accL[et] = __builtin_amdgcn_mfma_f32_16x16x32_bf16(aM, bM, accL[et], 0, 0, 0);
            accL[et] = __builtin_amdgcn_mfma_f32_16x16x32_bf16(aH, bL, accL[et], 0, 0, 0);
            accL[et] = __builtin_amdgcn_mfma_f32_16x16x32_bf16(aL, bH, accL[et], 0, 0, 0);
        }
        a0c = a0n; a1c = a1n;
    }

    // epilogue: transpose via LDS (aliased onto sB), coalesced partial writes
    __syncthreads();   // all waves done reading sB
    float* sled = reinterpret_cast<float*>(&sB[0][0][0]);   // 4 KB/wave used
#pragma unroll
    for (int et = 0; et < 4; ++et)
#pragma unroll
        for (int j = 0; j < 4; ++j)
            sled[w * 1024 + (et * 16 + lr) * 16 + lo * 4 + j]
                = accH[et][j] + accL[et][j];
    __syncthreads();
#pragma unroll
    for (int r = 0; r < 16; ++r) {
        const int e = r * 4 + lo;
        part[(size_t)(blockIdx.y * NEXP + e) * TOKENS + tok0 + lr]
            = sled[w * 1024 + e * 16 + lr];
    }
}

// combine splits in fp64 + bias, top-2, softmax (R6/R7-proven).
template<int S>
__global__ __launch_bounds__(256) void reduce_topk(
    const float* __restrict__ part, const float* __restrict__ b,
    float* __restrict__ out)
{
    __shared__ double sv[64][4][2];
    __shared__ int    si[64][4][2];
    const int t    = threadIdx.x;
    const int p4   = t & 3;
    const int slot = t >> 2;
    const int tok  = blockIdx.x * 64 + slot;

    double v[16];
#pragma unroll
    for (int j = 0; j < 16; ++j) v[j] = 0.0;
    for (int s = 0; s < S; ++s)
#pragma unroll
        for (int j = 0; j < 16; ++j)
            v[j] += (double)part[(size_t)((s << 6) + (p4 << 4) + j) * TOKENS + tok];
#pragma unroll
    for (int j = 0; j < 16; ++j) v[j] += (double)b[(p4 << 4) + j];

    double v1 = -1e300, v2 = -1e300; int i1 = 0, i2 = 0;
#pragma unroll
    for (int j = 0; j < 16; ++j) {
        const int e = (p4 << 4) + j;
        if (v[j] > v1)      { v2 = v1; i2 = i1; v1 = v[j]; i1 = e; }
        else if (v[j] > v2) { v2 = v[j]; i2 = e; }
    }
    sv[slot][p4][0] = v1; sv[slot][p4][1] = v2;
    si[slot][p4][0] = i1; si[slot][p4][1] = i2;
    __syncthreads();

    if (p4 == 0) {
        double m1 = -1e300, m2 = -1e300; int j1 = 0, j2 = 0;
#pragma unroll
        for (int p = 0; p < 4; ++p)   // ascending parts: ties keep lowest idx
#pragma unroll
            for (int r = 0; r < 2; ++r) {
                const double vv = sv[slot][p][r]; const int ii = si[slot][p][r];
                if (vv > m1)      { m2 = m1; j2 = j1; m1 = vv; j1 = ii; }
                else if (vv > m2) { m2 = vv; j2 = ii; }
            }
        const float e2  = expf((float)(m2 - m1));   // <= 1
        const float inv = 1.0f / (1.0f + e2);
        out[2 * tok]     = (float)j1;
        out[2 * tok + 1] = (float)j2;
        out[2 * TOKENS + 2 * tok]     = inv;
        out[2 * TOKENS + 2 * tok + 1] = e2 * inv;
    }
}

extern "C" void kernel_launch(void* const* d_in, const int* in_sizes, int n_in,
                              void* d_out, int out_size, void* d_ws, size_t ws_size,
                              hipStream_t stream) {
    const float* x = (const float*)d_in[0];
    const float* W = (const float*)d_in[1];
    const float* b = (const float*)d_in[2];
    float* out = (float*)d_out;
    unsigned short* Wp = (unsigned short*)d_ws;
    float* part = (float*)d_ws + WP_FLOATS;

    split_w<<<dim3(NEXP * EMB / 1024), dim3(256), 0, stream>>>(W, Wp);

    const size_t base = (size_t)WP_FLOATS * 4;
    const size_t per  = (size_t)NEXP * TOKENS * 4;   // 4.19 MB / split
    if (ws_size >= base + 4 * per) {         // 18.3 MB (proven in R7) -> 4/CU
        router_mfma<4><<<dim3(TOKENS / 64, 4), dim3(256), 0, stream>>>(x, Wp, part);
        reduce_topk<4><<<dim3(TOKENS / 64), dim3(256), 0, stream>>>(part, b, out);
    } else if (ws_size >= base + 2 * per) {
        router_mfma<2><<<dim3(TOKENS / 64, 2), dim3(256), 0, stream>>>(x, Wp, part);
        reduce_topk<2><<<dim3(TOKENS / 64), dim3(256), 0, stream>>>(part, b, out);
    } else {
        router_mfma<1><<<dim3(TOKENS / 64, 1), dim3(256), 0, stream>>>(x, Wp, part);
        reduce_topk<1><<<dim3(TOKENS / 64), dim3(256), 0, stream>>>(part, b, out);
    }
}